// Round 1
// baseline (56.457 us; speedup 1.0000x reference)
//
#include <hip/hip_runtime.h>

static constexpr int H = 2048;
static constexpr int W = 2048;
static constexpr int NPIX = H * W;
static constexpr int BLOCK = 256;
static constexpr int NBLOCKS = NPIX / BLOCK; // 16384

// Per-pixel JS divergence over 3x3 Gaussian-weighted neighbor PDFs.
// Identity used (sigma=1):
//   g_i = exp(-d_i/2), a_i = g_i/Gp, b_i analogous, m_i = (a_i+b_i)/2
//   2*div = sum a_i ln a_i + sum b_i ln b_i - 2 sum m_i ln m_i
//   sum a ln a = -0.5*sum(a_i*d_i) - ln Gp        (since sum a_i = 1)
// Output scalar = sum over all pixels of 2*div.
__global__ __launch_bounds__(BLOCK) void jsd_pixel_kernel(
    const float* __restrict__ real, const float* __restrict__ fake,
    float* __restrict__ partial)
{
    const int idx = blockIdx.x * BLOCK + threadIdx.x;
    const int y = idx >> 11;        // idx / W  (W = 2048)
    const int x = idx & (W - 1);    // idx % W

    const float rc = real[idx];
    const float fc = fake[idx];

    float gp[9], gq[9], dp[9], dq[9];
    float Gp = 0.f, Gq = 0.f;

    #pragma unroll
    for (int dy = -1; dy <= 1; ++dy) {
        #pragma unroll
        for (int dx = -1; dx <= 1; ++dx) {
            const int j = (dy + 1) * 3 + (dx + 1);
            const int yy = y + dy, xx = x + dx;
            // zero padding: OOB neighbor value is 0 (matches SAME zero pad)
            const bool ok = ((unsigned)yy < (unsigned)H) && ((unsigned)xx < (unsigned)W);
            const int o = yy * W + xx;
            const float rv = ok ? real[o] : 0.0f;
            const float fv = ok ? fake[o] : 0.0f;
            const float dr = rv - rc;
            const float df = fv - fc;
            dp[j] = dr * dr;
            dq[j] = df * df;
            gp[j] = __expf(-0.5f * dp[j]);
            gq[j] = __expf(-0.5f * dq[j]);
            Gp += gp[j];
            Gq += gq[j];
        }
    }

    const float invGp = __builtin_amdgcn_rcpf(Gp);
    const float invGq = __builtin_amdgcn_rcpf(Gq);

    float sad = 0.f, sbd = 0.f, smlm = 0.f;
    #pragma unroll
    for (int j = 0; j < 9; ++j) {
        const float a = gp[j] * invGp;
        const float b = gq[j] * invGq;
        const float m = 0.5f * (a + b);
        smlm = fmaf(m, __logf(m), smlm);
        sad  = fmaf(a, dp[j], sad);
        sbd  = fmaf(b, dq[j], sbd);
    }

    float contrib = -0.5f * sad - __logf(Gp)
                    -0.5f * sbd - __logf(Gq)
                    -2.0f * smlm;

    // wave64 shuffle reduce, then cross-wave via LDS
    #pragma unroll
    for (int off = 32; off > 0; off >>= 1)
        contrib += __shfl_down(contrib, off, 64);

    __shared__ float ws[BLOCK / 64];
    const int lane = threadIdx.x & 63;
    const int wid  = threadIdx.x >> 6;
    if (lane == 0) ws[wid] = contrib;
    __syncthreads();
    if (threadIdx.x == 0)
        partial[blockIdx.x] = ws[0] + ws[1] + ws[2] + ws[3];
}

// Deterministic final reduce of NBLOCKS partials (single block).
__global__ __launch_bounds__(BLOCK) void jsd_final_reduce(
    const float* __restrict__ partial, float* __restrict__ out)
{
    float s = 0.f;
    for (int i = threadIdx.x; i < NBLOCKS; i += BLOCK)
        s += partial[i];

    #pragma unroll
    for (int off = 32; off > 0; off >>= 1)
        s += __shfl_down(s, off, 64);

    __shared__ float ws[BLOCK / 64];
    const int lane = threadIdx.x & 63;
    const int wid  = threadIdx.x >> 6;
    if (lane == 0) ws[wid] = s;
    __syncthreads();
    if (threadIdx.x == 0)
        out[0] = ws[0] + ws[1] + ws[2] + ws[3];
}

extern "C" void kernel_launch(void* const* d_in, const int* in_sizes, int n_in,
                              void* d_out, int out_size, void* d_ws, size_t ws_size,
                              hipStream_t stream) {
    const float* real = (const float*)d_in[0];
    const float* fake = (const float*)d_in[1];
    float* out = (float*)d_out;
    float* partial = (float*)d_ws;   // NBLOCKS floats = 64 KiB

    jsd_pixel_kernel<<<NBLOCKS, BLOCK, 0, stream>>>(real, fake, partial);
    jsd_final_reduce<<<1, BLOCK, 0, stream>>>(partial, out);
}

// Round 2
// 28.618 us; speedup vs baseline: 1.9728x; 1.9728x over previous
//
#include <hip/hip_runtime.h>

static constexpr int H = 2048;
static constexpr int W = 2048;
static constexpr int BLOCK = 256;
static constexpr int PXT = 4;                         // pixels per thread
static constexpr int BLOCKS_PER_ROW = W / (BLOCK * PXT);  // 2
static constexpr int NBLOCKS = H * BLOCKS_PER_ROW;        // 4096
static constexpr int RBLOCK = 1024;

__device__ __forceinline__ float fexp2(float x) { return __builtin_amdgcn_exp2f(x); }
__device__ __forceinline__ float flog2(float x) { return __builtin_amdgcn_logf(x); }
__device__ __forceinline__ float frcp(float x)  { return __builtin_amdgcn_rcpf(x); }

// Per-pixel JS divergence over 3x3 Gaussian-weighted neighbor PDFs (sigma=1).
//   g_i = exp(-d_i/2)  (center: d=0, g=1)
//   contrib = -0.5*invGp*sum(gp_i*dp_i) - ln Gp  (same for q)  - 2*sum(m ln m)
// All logs/exps in base-2; ln2 factors folded at the end.
__global__ __launch_bounds__(BLOCK) void jsd_pixel_kernel(
    const float* __restrict__ real, const float* __restrict__ fake,
    float* __restrict__ partial)
{
    const int bid = blockIdx.x;
    const int y   = bid >> 1;                       // 2 blocks per row
    const int x0  = ((bid & 1) << 10) + (threadIdx.x << 2);

    constexpr float K   = -0.72134752044448170f;   // -0.5*log2(e)
    constexpr float LN2 =  0.69314718055994531f;

    // rv[r][c], r: 0=y-1, 1=y, 2=y+1 ; c: 0 = x0-1 .. 5 = x0+4
    float rv[3][6], fv[3][6];
    const int base = y * W + x0;
    const bool hasL = (x0 > 0);
    const bool hasR = (x0 + PXT < W);

    {   // middle row
        const float4 m4 = *(const float4*)(real + base);
        rv[1][1] = m4.x; rv[1][2] = m4.y; rv[1][3] = m4.z; rv[1][4] = m4.w;
        rv[1][0] = hasL ? real[base - 1] : 0.f;
        rv[1][5] = hasR ? real[base + PXT] : 0.f;
        const float4 f4 = *(const float4*)(fake + base);
        fv[1][1] = f4.x; fv[1][2] = f4.y; fv[1][3] = f4.z; fv[1][4] = f4.w;
        fv[1][0] = hasL ? fake[base - 1] : 0.f;
        fv[1][5] = hasR ? fake[base + PXT] : 0.f;
    }
    if (y > 0) {   // row above (wave-uniform branch)
        const int b = base - W;
        const float4 m4 = *(const float4*)(real + b);
        rv[0][1] = m4.x; rv[0][2] = m4.y; rv[0][3] = m4.z; rv[0][4] = m4.w;
        rv[0][0] = hasL ? real[b - 1] : 0.f;
        rv[0][5] = hasR ? real[b + PXT] : 0.f;
        const float4 f4 = *(const float4*)(fake + b);
        fv[0][1] = f4.x; fv[0][2] = f4.y; fv[0][3] = f4.z; fv[0][4] = f4.w;
        fv[0][0] = hasL ? fake[b - 1] : 0.f;
        fv[0][5] = hasR ? fake[b + PXT] : 0.f;
    } else {
        #pragma unroll
        for (int c = 0; c < 6; ++c) { rv[0][c] = 0.f; fv[0][c] = 0.f; }
    }
    if (y < H - 1) {   // row below
        const int b = base + W;
        const float4 m4 = *(const float4*)(real + b);
        rv[2][1] = m4.x; rv[2][2] = m4.y; rv[2][3] = m4.z; rv[2][4] = m4.w;
        rv[2][0] = hasL ? real[b - 1] : 0.f;
        rv[2][5] = hasR ? real[b + PXT] : 0.f;
        const float4 f4 = *(const float4*)(fake + b);
        fv[2][1] = f4.x; fv[2][2] = f4.y; fv[2][3] = f4.z; fv[2][4] = f4.w;
        fv[2][0] = hasL ? fake[b - 1] : 0.f;
        fv[2][5] = hasR ? fake[b + PXT] : 0.f;
    } else {
        #pragma unroll
        for (int c = 0; c < 6; ++c) { rv[2][c] = 0.f; fv[2][c] = 0.f; }
    }

    // horizontal pair diffs (middle row), shared between adjacent pixels
    float hsp[5], hep[5], hsq[5], heq[5];
    #pragma unroll
    for (int j = 0; j < 5; ++j) {
        const float dr = rv[1][j + 1] - rv[1][j];
        hsp[j] = dr * dr;
        hep[j] = fexp2(hsp[j] * K);
        const float df = fv[1][j + 1] - fv[1][j];
        hsq[j] = df * df;
        heq[j] = fexp2(hsq[j] * K);
    }

    float acc = 0.f;
    #pragma unroll
    for (int k = 0; k < PXT; ++k) {
        const float cr = rv[1][k + 1];
        const float cf = fv[1][k + 1];

        // 6 vertical/diagonal neighbors: up k..k+2, down k..k+2
        float vsp[6], vep[6], vsq[6], veq[6];
        #pragma unroll
        for (int j = 0; j < 3; ++j) {
            float d;
            d = rv[0][k + j] - cr; vsp[j] = d * d;     vep[j] = fexp2(vsp[j] * K);
            d = fv[0][k + j] - cf; vsq[j] = d * d;     veq[j] = fexp2(vsq[j] * K);
            d = rv[2][k + j] - cr; vsp[3 + j] = d * d; vep[3 + j] = fexp2(vsp[3 + j] * K);
            d = fv[2][k + j] - cf; vsq[3 + j] = d * d; veq[3 + j] = fexp2(vsq[3 + j] * K);
        }

        float Gp = 1.f + hep[k] + hep[k + 1];
        float Gq = 1.f + heq[k] + heq[k + 1];
        float sadp = hep[k] * hsp[k] + hep[k + 1] * hsp[k + 1];
        float sadq = heq[k] * hsq[k] + heq[k + 1] * hsq[k + 1];
        #pragma unroll
        for (int j = 0; j < 6; ++j) {
            Gp += vep[j];
            Gq += veq[j];
            sadp = fmaf(vep[j], vsp[j], sadp);
            sadq = fmaf(veq[j], vsq[j], sadq);
        }

        const float invGp = frcp(Gp);
        const float invGq = frcp(Gq);
        const float hp = 0.5f * invGp;
        const float hq = 0.5f * invGq;

        // sum of m*log2(m) over 9 taps
        float mll;
        {
            const float m = hp + hq;                 // center tap (gp=gq=1)
            mll = m * flog2(m);
        }
        {
            float m = fmaf(hep[k], hp, heq[k] * hq);
            mll = fmaf(m, flog2(m), mll);
            m = fmaf(hep[k + 1], hp, heq[k + 1] * hq);
            mll = fmaf(m, flog2(m), mll);
        }
        #pragma unroll
        for (int j = 0; j < 6; ++j) {
            const float m = fmaf(vep[j], hp, veq[j] * hq);
            mll = fmaf(m, flog2(m), mll);
        }

        const float logs = flog2(Gp) + flog2(Gq) + 2.f * mll;
        acc += -0.5f * fmaf(invGp, sadp, invGq * sadq) - LN2 * logs;
    }

    // wave64 shuffle reduce, then cross-wave via LDS
    #pragma unroll
    for (int off = 32; off > 0; off >>= 1)
        acc += __shfl_down(acc, off, 64);

    __shared__ float ws[BLOCK / 64];
    const int lane = threadIdx.x & 63;
    const int wid  = threadIdx.x >> 6;
    if (lane == 0) ws[wid] = acc;
    __syncthreads();
    if (threadIdx.x == 0)
        partial[blockIdx.x] = ws[0] + ws[1] + ws[2] + ws[3];
}

// Deterministic final reduce of NBLOCKS partials (single block, 16 waves).
__global__ __launch_bounds__(RBLOCK) void jsd_final_reduce(
    const float* __restrict__ partial, float* __restrict__ out)
{
    float s = 0.f;
    #pragma unroll
    for (int i = 0; i < NBLOCKS / RBLOCK; ++i)
        s += partial[i * RBLOCK + threadIdx.x];

    #pragma unroll
    for (int off = 32; off > 0; off >>= 1)
        s += __shfl_down(s, off, 64);

    __shared__ float ws[RBLOCK / 64];
    const int lane = threadIdx.x & 63;
    const int wid  = threadIdx.x >> 6;
    if (lane == 0) ws[wid] = s;
    __syncthreads();
    if (threadIdx.x == 0) {
        float t = 0.f;
        #pragma unroll
        for (int i = 0; i < RBLOCK / 64; ++i) t += ws[i];
        out[0] = t;
    }
}

extern "C" void kernel_launch(void* const* d_in, const int* in_sizes, int n_in,
                              void* d_out, int out_size, void* d_ws, size_t ws_size,
                              hipStream_t stream) {
    const float* real = (const float*)d_in[0];
    const float* fake = (const float*)d_in[1];
    float* out = (float*)d_out;
    float* partial = (float*)d_ws;   // NBLOCKS floats = 16 KiB

    jsd_pixel_kernel<<<NBLOCKS, BLOCK, 0, stream>>>(real, fake, partial);
    jsd_final_reduce<<<1, RBLOCK, 0, stream>>>(partial, out);
}